// Round 8
// baseline (129.044 us; speedup 1.0000x reference)
//
#include <hip/hip_runtime.h>
#include <hip/hip_bf16.h>

typedef short    bf16x8 __attribute__((ext_vector_type(8)));
typedef float    f32x4  __attribute__((ext_vector_type(4)));
typedef _Float16 f16x4  __attribute__((ext_vector_type(4)));

constexpr int BB  = 4096;
constexpr int AA  = 64;
constexpr int ED  = 10;
constexpr int P1N = 32, P2N = 128, P3N = 256;
constexpr int PT  = 416;          // = 13 * 32
constexpr int NKS = 13;           // K-steps of 32
constexpr int KSPL = 7;           // k-half split: [0,7) / [7,13)
constexpr int BCH = 32;           // b rows per block
constexpr int NCH = 4;            // a-channels per block (fp16x4 per slot)

__device__ inline short f2bf(float f) {
  __hip_bfloat16 h = __float2bfloat16(f);
  short s;
  __builtin_memcpy(&s, &h, 2);
  return s;
}

__device__ __forceinline__ f32x4 h2f(f16x4 h) {
  f32x4 r;
  r[0] = (float)h[0]; r[1] = (float)h[1]; r[2] = (float)h[2]; r[3] = (float)h[3];
  return r;
}

// ---------------------------------------------------------------------------
// idxs[p] = (sa*8) | (sb*8)<<10 | (sc*8)<<20  -- BYTE offsets into an f16x4
// row (8 B/slot). Unused slots = 64 (constant-1).
// ---------------------------------------------------------------------------
__global__ void build_idx_kernel(
    const int* __restrict__ i1, const int* __restrict__ l1,
    const int* __restrict__ i2, const int* __restrict__ j2,
    const int* __restrict__ l2, const int* __restrict__ m2,
    const int* __restrict__ i3, const int* __restrict__ j3,
    const int* __restrict__ f3, const int* __restrict__ l3,
    const int* __restrict__ m3, const int* __restrict__ g3,
    unsigned* __restrict__ idxs) {
  const int p = threadIdx.x;
  if (p >= PT) return;
  unsigned sa, sb = 64, sc = 64;
  if (p < P1N) {
    sa = i1[p] * 4 + l1[p];
  } else if (p < P1N + P2N) {
    int pp = p - P1N;
    sa = i2[pp] * 4 + l2[pp];
    sb = j2[pp] * 4 + m2[pp];
  } else {
    int pp = p - P1N - P2N;
    sa = i3[pp] * 4 + l3[pp];
    sb = j3[pp] * 4 + m3[pp];
    sc = f3[pp] * 4 + g3[pp];
  }
  idxs[p] = (sa * 8) | ((sb * 8) << 10) | ((sc * 8) << 20);
}

// ---------------------------------------------------------------------------
// B-frag table: cwb[a][ks][lane][j] = bf16( coeff[p] * w[e,k[p],q[p],a] )
// p = ks*32 + (lane>>4)*8 + j, e = lane&15 (0 for e>=10).
// ---------------------------------------------------------------------------
__global__ void build_cwb_kernel(
    const float* __restrict__ w1, const float* __restrict__ w2, const float* __restrict__ w3,
    const float* __restrict__ c1, const float* __restrict__ c2, const float* __restrict__ c3,
    const int* __restrict__ k1, const int* __restrict__ q1,
    const int* __restrict__ k2, const int* __restrict__ q2,
    const int* __restrict__ k3, const int* __restrict__ q3,
    short* __restrict__ cwb) {
  const int a  = blockIdx.x & 63;
  const int ks = blockIdx.x >> 6;   // 0..12
  const int l  = threadIdx.x;       // 0..63
  const int grp = l >> 4, e = l & 15;
  short* dst = cwb + (((size_t)a * NKS + ks) * 64 + l) * 8;
  #pragma unroll
  for (int j = 0; j < 8; ++j) {
    const int p = ks * 32 + grp * 8 + j;
    float v = 0.f;
    if (e < ED) {
      const float* w; float coeff; int k, q, K, Q;
      if (p < P1N)            { w = w1; coeff = c1[p]; k = k1[p]; q = q1[p]; K = 4;  Q = 2; }
      else if (p < P1N + P2N) { int pp = p - P1N;       w = w2; coeff = c2[pp]; k = k2[pp]; q = q2[pp]; K = 16; Q = 4; }
      else                    { int pp = p - P1N - P2N; w = w3; coeff = c3[pp]; k = k3[pp]; q = q3[pp]; K = 32; Q = 6; }
      v = coeff * w[(((size_t)e * K + k) * Q + q) * AA + a];
    }
    dst[j] = f2bf(v);
  }
}

// ---------------------------------------------------------------------------
// K-step: one ds_read_b64 (fp16x4) gather serves 4 a-channels.
// ---------------------------------------------------------------------------
template <int NF>
__device__ __forceinline__ void kstep4(const char* __restrict__ rowb,
                                       const uint4* __restrict__ ip, int ks,
                                       const bf16x8* __restrict__ cw0,
                                       const bf16x8* __restrict__ cw1,
                                       const bf16x8* __restrict__ cw2,
                                       const bf16x8* __restrict__ cw3,
                                       f32x4& ac0, f32x4& ac1, f32x4& ac2, f32x4& ac3) {
  const uint4 iA = ip[ks * 8 + 0];
  const uint4 iB = ip[ks * 8 + 1];
  const bf16x8 b0 = cw0[ks * 64];
  const bf16x8 b1 = cw1[ks * 64];
  const bf16x8 b2 = cw2[ks * 64];
  const bf16x8 b3 = cw3[ks * 64];
  const unsigned pks[8] = {iA.x, iA.y, iA.z, iA.w, iB.x, iB.y, iB.z, iB.w};
  bf16x8 a0, a1, a2, a3;
  #pragma unroll
  for (int j = 0; j < 8; ++j) {
    const unsigned pk = pks[j];
    f32x4 v = h2f(*(const f16x4*)(rowb + (pk & 1023u)));
    if (NF >= 2) v = v * h2f(*(const f16x4*)(rowb + ((pk >> 10) & 1023u)));
    if (NF >= 3) v = v * h2f(*(const f16x4*)(rowb + (pk >> 20)));
    a0[j] = f2bf(v[0]); a1[j] = f2bf(v[1]); a2[j] = f2bf(v[2]); a3[j] = f2bf(v[3]);
  }
  ac0 = __builtin_amdgcn_mfma_f32_16x16x32_bf16(a0, b0, ac0, 0, 0, 0);
  ac1 = __builtin_amdgcn_mfma_f32_16x16x32_bf16(a1, b1, ac1, 0, 0, 0);
  ac2 = __builtin_amdgcn_mfma_f32_16x16x32_bf16(a2, b2, ac2, 0, 0, 0);
  ac3 = __builtin_amdgcn_mfma_f32_16x16x32_bf16(a3, b3, ac3, 0, 0, 0);
}

// ---------------------------------------------------------------------------
// Main: block = a-quad x 32 b's; fp16x4 x-tile (18.8 KB) -> 8 blocks/CU.
// 4 waves = 2 M-tiles x 2 k-halves; partials combined via LDS scratch.
// ---------------------------------------------------------------------------
__global__ __launch_bounds__(256, 8)
void contract_kernel(const float* __restrict__ x, const float* __restrict__ y,
                     const unsigned* __restrict__ idxs,
                     const bf16x8* __restrict__ cwb,
                     float* __restrict__ out) {
  __shared__ f16x4 xls[BCH][65];   // slot 64 = {1,1,1,1}; 16.25 KB
  __shared__ float yls[BCH][17];   // e padded to 16 with zeros

  const int t  = threadIdx.x;
  const int a0 = (blockIdx.x & 15) * NCH;
  const int b0 = (blockIdx.x >> 4) * BCH;

  // Stage x: lane = slot; 4 coalesced dword loads -> cvt f16 -> one b64 write.
  for (int u = t; u < BCH * 64; u += 256) {
    const int b = u >> 6, s = u & 63;
    const float* xb = x + (size_t)(b0 + b) * 4096 + a0 * 64 + s;
    f16x4 v;
    v[0] = (_Float16)xb[0];
    v[1] = (_Float16)xb[64];
    v[2] = (_Float16)xb[128];
    v[3] = (_Float16)xb[192];
    xls[b][s] = v;
  }
  if (t < BCH) {
    f16x4 one;
    one[0] = one[1] = one[2] = one[3] = (_Float16)1.0f;
    xls[t][64] = one;
    const float* yb = y + (size_t)(b0 + t) * ED;
    #pragma unroll
    for (int e = 0; e < ED; ++e) yls[t][e] = yb[e];
    #pragma unroll
    for (int e = ED; e < 16; ++e) yls[t][e] = 0.f;
  }
  __syncthreads();

  const int wv = t >> 6, l = t & 63, grp = l >> 4, er = l & 15;
  const int mt = wv & 1;            // M-tile (16 rows)
  const int kh = wv >> 1;           // k-half
  const char* __restrict__ rowb = (const char*)&xls[mt * 16 + er][0];
  const bf16x8* __restrict__ cw0 = cwb + ((size_t)(a0 + 0) * NKS) * 64 + l;
  const bf16x8* __restrict__ cw1 = cwb + ((size_t)(a0 + 1) * NKS) * 64 + l;
  const bf16x8* __restrict__ cw2 = cwb + ((size_t)(a0 + 2) * NKS) * 64 + l;
  const bf16x8* __restrict__ cw3 = cwb + ((size_t)(a0 + 3) * NKS) * 64 + l;
  const uint4*  __restrict__ ip  = (const uint4*)idxs + grp * 2;

  f32x4 ac0 = {0.f, 0.f, 0.f, 0.f};
  f32x4 ac1 = {0.f, 0.f, 0.f, 0.f};
  f32x4 ac2 = {0.f, 0.f, 0.f, 0.f};
  f32x4 ac3 = {0.f, 0.f, 0.f, 0.f};

  if (kh == 0) {
    kstep4<1>(rowb, ip, 0, cw0, cw1, cw2, cw3, ac0, ac1, ac2, ac3);  // path1
    #pragma unroll 2
    for (int ks = 1; ks < 5; ++ks)                                    // path2
      kstep4<2>(rowb, ip, ks, cw0, cw1, cw2, cw3, ac0, ac1, ac2, ac3);
    #pragma unroll 2
    for (int ks = 5; ks < KSPL; ++ks)                                 // path3
      kstep4<3>(rowb, ip, ks, cw0, cw1, cw2, cw3, ac0, ac1, ac2, ac3);
  } else {
    #pragma unroll 2
    for (int ks = KSPL; ks < NKS; ++ks)                               // path3
      kstep4<3>(rowb, ip, ks, cw0, cw1, cw2, cw3, ac0, ac1, ac2, ac3);
  }

  // Combine k-halves via LDS scratch (stride 17: bijective banks, 8.7 KB).
  __syncthreads();
  float* scr = (float*)&xls[0][0];
  const int sbase = (mt * 64 + l) * 17;
  if (kh == 1) {
    #pragma unroll
    for (int v = 0; v < 4; ++v) {
      scr[sbase + v + 0]  = ac0[v];
      scr[sbase + v + 4]  = ac1[v];
      scr[sbase + v + 8]  = ac2[v];
      scr[sbase + v + 12] = ac3[v];
    }
  }
  __syncthreads();
  if (kh == 0) {
    #pragma unroll
    for (int v = 0; v < 4; ++v) {
      ac0[v] += scr[sbase + v + 0];
      ac1[v] += scr[sbase + v + 4];
      ac2[v] += scr[sbase + v + 8];
      ac3[v] += scr[sbase + v + 12];
    }
    // Epilogue: D[row = mt*16+grp*4+v][col = er], y-weight, reduce over e.
    #pragma unroll
    for (int c = 0; c < NCH; ++c) {
      const f32x4 acc = c == 0 ? ac0 : c == 1 ? ac1 : c == 2 ? ac2 : ac3;
      float s0 = acc[0] * yls[mt * 16 + grp * 4 + 0][er];
      float s1 = acc[1] * yls[mt * 16 + grp * 4 + 1][er];
      float s2 = acc[2] * yls[mt * 16 + grp * 4 + 2][er];
      float s3 = acc[3] * yls[mt * 16 + grp * 4 + 3][er];
      #pragma unroll
      for (int m = 1; m < 16; m <<= 1) {
        s0 += __shfl_xor(s0, m);
        s1 += __shfl_xor(s1, m);
        s2 += __shfl_xor(s2, m);
        s3 += __shfl_xor(s3, m);
      }
      if (er < 4) {
        const float sv = er == 0 ? s0 : er == 1 ? s1 : er == 2 ? s2 : s3;
        out[(size_t)(b0 + mt * 16 + grp * 4 + er) * AA + (a0 + c)] = sv;
      }
    }
  }
}

// ---------------------------------------------------------------------------
extern "C" void kernel_launch(void* const* d_in, const int* in_sizes, int n_in,
                              void* d_out, int out_size, void* d_ws, size_t ws_size,
                              hipStream_t stream) {
  const float* x  = (const float*)d_in[0];
  const float* y  = (const float*)d_in[1];
  const float* w1 = (const float*)d_in[2];
  const float* w2 = (const float*)d_in[3];
  const float* w3 = (const float*)d_in[4];
  const float* c1 = (const float*)d_in[5];
  const float* c2 = (const float*)d_in[6];
  const float* c3 = (const float*)d_in[7];
  const int* i1 = (const int*)d_in[8];
  const int* l1 = (const int*)d_in[9];
  const int* k1 = (const int*)d_in[10];
  const int* q1 = (const int*)d_in[11];
  const int* i2 = (const int*)d_in[12];
  const int* j2 = (const int*)d_in[13];
  const int* l2 = (const int*)d_in[14];
  const int* m2 = (const int*)d_in[15];
  const int* k2 = (const int*)d_in[16];
  const int* q2 = (const int*)d_in[17];
  const int* i3 = (const int*)d_in[18];
  const int* j3 = (const int*)d_in[19];
  const int* f3 = (const int*)d_in[20];
  const int* l3 = (const int*)d_in[21];
  const int* m3 = (const int*)d_in[22];
  const int* g3 = (const int*)d_in[23];
  const int* k3 = (const int*)d_in[24];
  const int* q3 = (const int*)d_in[25];

  unsigned* idxs = (unsigned*)d_ws;                    // 416*4 B
  short*    cwb  = (short*)((char*)d_ws + 4096);       // 832 KB

  build_idx_kernel<<<1, 448, 0, stream>>>(i1, l1, i2, j2, l2, m2,
                                          i3, j3, f3, l3, m3, g3, idxs);
  build_cwb_kernel<<<AA * NKS, 64, 0, stream>>>(w1, w2, w3, c1, c2, c3,
                                                k1, q1, k2, q2, k3, q3, cwb);
  contract_kernel<<<(AA / NCH) * (BB / BCH), 256, 0, stream>>>(
      x, y, idxs, (const bf16x8*)cwb, (float*)d_out);
}

// Round 9
// 48.611 us; speedup vs baseline: 2.6546x; 2.6546x over previous
//
#include <hip/hip_runtime.h>
#include <hip/hip_bf16.h>

typedef short    bf16x8 __attribute__((ext_vector_type(8)));
typedef float    f32x4  __attribute__((ext_vector_type(4)));
typedef _Float16 f16x4  __attribute__((ext_vector_type(4)));

constexpr int BB  = 4096;
constexpr int AA  = 64;
constexpr int ED  = 10;
constexpr int P1N = 32, P2N = 128, P3N = 256;
constexpr int PT  = 416;          // = 13 * 32
constexpr int NKS = 13;           // K-steps of 32
constexpr int KSPL = 7;           // k-half split: [0,7) / [7,13)
constexpr int BCH = 32;           // b rows per block
constexpr int NCH = 4;            // a-channels per block (fp16x4 per slot)

__device__ inline short f2bf(float f) {
  __hip_bfloat16 h = __float2bfloat16(f);
  short s;
  __builtin_memcpy(&s, &h, 2);
  return s;
}

__device__ __forceinline__ f32x4 h2f(f16x4 h) {
  f32x4 r;
  r[0] = (float)h[0]; r[1] = (float)h[1]; r[2] = (float)h[2]; r[3] = (float)h[3];
  return r;
}

// ---------------------------------------------------------------------------
// idxs[p] = (sa*8) | (sb*8)<<10 | (sc*8)<<20  -- BYTE offsets into an f16x4
// row (8 B/slot). Unused slots = 64 (constant-1).
// ---------------------------------------------------------------------------
__global__ void build_idx_kernel(
    const int* __restrict__ i1, const int* __restrict__ l1,
    const int* __restrict__ i2, const int* __restrict__ j2,
    const int* __restrict__ l2, const int* __restrict__ m2,
    const int* __restrict__ i3, const int* __restrict__ j3,
    const int* __restrict__ f3, const int* __restrict__ l3,
    const int* __restrict__ m3, const int* __restrict__ g3,
    unsigned* __restrict__ idxs) {
  const int p = threadIdx.x;
  if (p >= PT) return;
  unsigned sa, sb = 64, sc = 64;
  if (p < P1N) {
    sa = i1[p] * 4 + l1[p];
  } else if (p < P1N + P2N) {
    int pp = p - P1N;
    sa = i2[pp] * 4 + l2[pp];
    sb = j2[pp] * 4 + m2[pp];
  } else {
    int pp = p - P1N - P2N;
    sa = i3[pp] * 4 + l3[pp];
    sb = j3[pp] * 4 + m3[pp];
    sc = f3[pp] * 4 + g3[pp];
  }
  idxs[p] = (sa * 8) | ((sb * 8) << 10) | ((sc * 8) << 20);
}

// ---------------------------------------------------------------------------
// B-frag table: cwb[a][ks][lane][j] = bf16( coeff[p] * w[e,k[p],q[p],a] )
// p = ks*32 + (lane>>4)*8 + j, e = lane&15 (0 for e>=10).
// ---------------------------------------------------------------------------
__global__ void build_cwb_kernel(
    const float* __restrict__ w1, const float* __restrict__ w2, const float* __restrict__ w3,
    const float* __restrict__ c1, const float* __restrict__ c2, const float* __restrict__ c3,
    const int* __restrict__ k1, const int* __restrict__ q1,
    const int* __restrict__ k2, const int* __restrict__ q2,
    const int* __restrict__ k3, const int* __restrict__ q3,
    short* __restrict__ cwb) {
  const int a  = blockIdx.x & 63;
  const int ks = blockIdx.x >> 6;   // 0..12
  const int l  = threadIdx.x;       // 0..63
  const int grp = l >> 4, e = l & 15;
  short* dst = cwb + (((size_t)a * NKS + ks) * 64 + l) * 8;
  #pragma unroll
  for (int j = 0; j < 8; ++j) {
    const int p = ks * 32 + grp * 8 + j;
    float v = 0.f;
    if (e < ED) {
      const float* w; float coeff; int k, q, K, Q;
      if (p < P1N)            { w = w1; coeff = c1[p]; k = k1[p]; q = q1[p]; K = 4;  Q = 2; }
      else if (p < P1N + P2N) { int pp = p - P1N;       w = w2; coeff = c2[pp]; k = k2[pp]; q = q2[pp]; K = 16; Q = 4; }
      else                    { int pp = p - P1N - P2N; w = w3; coeff = c3[pp]; k = k3[pp]; q = q3[pp]; K = 32; Q = 6; }
      v = coeff * w[(((size_t)e * K + k) * Q + q) * AA + a];
    }
    dst[j] = f2bf(v);
  }
}

// ---------------------------------------------------------------------------
// K-step: one ds_read_b64 (fp16x4) gather serves 4 a-channels.
// ---------------------------------------------------------------------------
template <int NF>
__device__ __forceinline__ void kstep4(const char* __restrict__ rowb,
                                       const uint4* __restrict__ ip, int ks,
                                       const bf16x8* __restrict__ cw0,
                                       const bf16x8* __restrict__ cw1,
                                       const bf16x8* __restrict__ cw2,
                                       const bf16x8* __restrict__ cw3,
                                       f32x4& ac0, f32x4& ac1, f32x4& ac2, f32x4& ac3) {
  const uint4 iA = ip[ks * 8 + 0];
  const uint4 iB = ip[ks * 8 + 1];
  const bf16x8 b0 = cw0[ks * 64];
  const bf16x8 b1 = cw1[ks * 64];
  const bf16x8 b2 = cw2[ks * 64];
  const bf16x8 b3 = cw3[ks * 64];
  const unsigned pks[8] = {iA.x, iA.y, iA.z, iA.w, iB.x, iB.y, iB.z, iB.w};
  bf16x8 a0, a1, a2, a3;
  #pragma unroll
  for (int j = 0; j < 8; ++j) {
    const unsigned pk = pks[j];
    f32x4 v = h2f(*(const f16x4*)(rowb + (pk & 1023u)));
    if (NF >= 2) v = v * h2f(*(const f16x4*)(rowb + ((pk >> 10) & 1023u)));
    if (NF >= 3) v = v * h2f(*(const f16x4*)(rowb + (pk >> 20)));
    a0[j] = f2bf(v[0]); a1[j] = f2bf(v[1]); a2[j] = f2bf(v[2]); a3[j] = f2bf(v[3]);
  }
  ac0 = __builtin_amdgcn_mfma_f32_16x16x32_bf16(a0, b0, ac0, 0, 0, 0);
  ac1 = __builtin_amdgcn_mfma_f32_16x16x32_bf16(a1, b1, ac1, 0, 0, 0);
  ac2 = __builtin_amdgcn_mfma_f32_16x16x32_bf16(a2, b2, ac2, 0, 0, 0);
  ac3 = __builtin_amdgcn_mfma_f32_16x16x32_bf16(a3, b3, ac3, 0, 0, 0);
}

// ---------------------------------------------------------------------------
// Main: block = a-quad x 32 b's; fp16x4 x-tile (18.9 KB LDS).
// __launch_bounds__(256,4): 128-VGPR budget -> NO SPILL (r8 lesson: (256,8)
// forced a 64-VGPR cap and spilled 350 MB to scratch).
// 4 waves = 2 M-tiles x 2 k-halves; partials combined via LDS scratch.
// ---------------------------------------------------------------------------
__global__ __launch_bounds__(256, 4)
void contract_kernel(const float* __restrict__ x, const float* __restrict__ y,
                     const unsigned* __restrict__ idxs,
                     const bf16x8* __restrict__ cwb,
                     float* __restrict__ out) {
  __shared__ f16x4 xls[BCH][65];   // slot 64 = {1,1,1,1}; 16.25 KB
  __shared__ float yls[BCH][17];   // e padded to 16 with zeros

  const int t  = threadIdx.x;
  const int a0 = (blockIdx.x & 15) * NCH;
  const int b0 = (blockIdx.x >> 4) * BCH;

  // Stage x: lane = slot; 4 coalesced dword loads -> cvt f16 -> one b64 write.
  for (int u = t; u < BCH * 64; u += 256) {
    const int b = u >> 6, s = u & 63;
    const float* xb = x + (size_t)(b0 + b) * 4096 + a0 * 64 + s;
    f16x4 v;
    v[0] = (_Float16)xb[0];
    v[1] = (_Float16)xb[64];
    v[2] = (_Float16)xb[128];
    v[3] = (_Float16)xb[192];
    xls[b][s] = v;
  }
  if (t < BCH) {
    f16x4 one;
    one[0] = one[1] = one[2] = one[3] = (_Float16)1.0f;
    xls[t][64] = one;
    const float* yb = y + (size_t)(b0 + t) * ED;
    #pragma unroll
    for (int e = 0; e < ED; ++e) yls[t][e] = yb[e];
    #pragma unroll
    for (int e = ED; e < 16; ++e) yls[t][e] = 0.f;
  }
  __syncthreads();

  const int wv = t >> 6, l = t & 63, grp = l >> 4, er = l & 15;
  const int mt = wv & 1;            // M-tile (16 rows)
  const int kh = wv >> 1;           // k-half
  const char* __restrict__ rowb = (const char*)&xls[mt * 16 + er][0];
  const bf16x8* __restrict__ cw0 = cwb + ((size_t)(a0 + 0) * NKS) * 64 + l;
  const bf16x8* __restrict__ cw1 = cwb + ((size_t)(a0 + 1) * NKS) * 64 + l;
  const bf16x8* __restrict__ cw2 = cwb + ((size_t)(a0 + 2) * NKS) * 64 + l;
  const bf16x8* __restrict__ cw3 = cwb + ((size_t)(a0 + 3) * NKS) * 64 + l;
  const uint4*  __restrict__ ip  = (const uint4*)idxs + grp * 2;

  f32x4 ac0 = {0.f, 0.f, 0.f, 0.f};
  f32x4 ac1 = {0.f, 0.f, 0.f, 0.f};
  f32x4 ac2 = {0.f, 0.f, 0.f, 0.f};
  f32x4 ac3 = {0.f, 0.f, 0.f, 0.f};

  if (kh == 0) {
    kstep4<1>(rowb, ip, 0, cw0, cw1, cw2, cw3, ac0, ac1, ac2, ac3);  // path1
    #pragma unroll 2
    for (int ks = 1; ks < 5; ++ks)                                    // path2
      kstep4<2>(rowb, ip, ks, cw0, cw1, cw2, cw3, ac0, ac1, ac2, ac3);
    #pragma unroll 2
    for (int ks = 5; ks < KSPL; ++ks)                                 // path3
      kstep4<3>(rowb, ip, ks, cw0, cw1, cw2, cw3, ac0, ac1, ac2, ac3);
  } else {
    #pragma unroll 2
    for (int ks = KSPL; ks < NKS; ++ks)                               // path3
      kstep4<3>(rowb, ip, ks, cw0, cw1, cw2, cw3, ac0, ac1, ac2, ac3);
  }

  // Combine k-halves via LDS scratch (stride 17: bijective banks, 8.7 KB).
  __syncthreads();
  float* scr = (float*)&xls[0][0];
  const int sbase = (mt * 64 + l) * 17;
  if (kh == 1) {
    #pragma unroll
    for (int v = 0; v < 4; ++v) {
      scr[sbase + v + 0]  = ac0[v];
      scr[sbase + v + 4]  = ac1[v];
      scr[sbase + v + 8]  = ac2[v];
      scr[sbase + v + 12] = ac3[v];
    }
  }
  __syncthreads();
  if (kh == 0) {
    #pragma unroll
    for (int v = 0; v < 4; ++v) {
      ac0[v] += scr[sbase + v + 0];
      ac1[v] += scr[sbase + v + 4];
      ac2[v] += scr[sbase + v + 8];
      ac3[v] += scr[sbase + v + 12];
    }
    // Epilogue: D[row = mt*16+grp*4+v][col = er], y-weight, reduce over e.
    #pragma unroll
    for (int c = 0; c < NCH; ++c) {
      const f32x4 acc = c == 0 ? ac0 : c == 1 ? ac1 : c == 2 ? ac2 : ac3;
      float s0 = acc[0] * yls[mt * 16 + grp * 4 + 0][er];
      float s1 = acc[1] * yls[mt * 16 + grp * 4 + 1][er];
      float s2 = acc[2] * yls[mt * 16 + grp * 4 + 2][er];
      float s3 = acc[3] * yls[mt * 16 + grp * 4 + 3][er];
      #pragma unroll
      for (int m = 1; m < 16; m <<= 1) {
        s0 += __shfl_xor(s0, m);
        s1 += __shfl_xor(s1, m);
        s2 += __shfl_xor(s2, m);
        s3 += __shfl_xor(s3, m);
      }
      if (er < 4) {
        const float sv = er == 0 ? s0 : er == 1 ? s1 : er == 2 ? s2 : s3;
        out[(size_t)(b0 + mt * 16 + grp * 4 + er) * AA + (a0 + c)] = sv;
      }
    }
  }
}

// ---------------------------------------------------------------------------
extern "C" void kernel_launch(void* const* d_in, const int* in_sizes, int n_in,
                              void* d_out, int out_size, void* d_ws, size_t ws_size,
                              hipStream_t stream) {
  const float* x  = (const float*)d_in[0];
  const float* y  = (const float*)d_in[1];
  const float* w1 = (const float*)d_in[2];
  const float* w2 = (const float*)d_in[3];
  const float* w3 = (const float*)d_in[4];
  const float* c1 = (const float*)d_in[5];
  const float* c2 = (const float*)d_in[6];
  const float* c3 = (const float*)d_in[7];
  const int* i1 = (const int*)d_in[8];
  const int* l1 = (const int*)d_in[9];
  const int* k1 = (const int*)d_in[10];
  const int* q1 = (const int*)d_in[11];
  const int* i2 = (const int*)d_in[12];
  const int* j2 = (const int*)d_in[13];
  const int* l2 = (const int*)d_in[14];
  const int* m2 = (const int*)d_in[15];
  const int* k2 = (const int*)d_in[16];
  const int* q2 = (const int*)d_in[17];
  const int* i3 = (const int*)d_in[18];
  const int* j3 = (const int*)d_in[19];
  const int* f3 = (const int*)d_in[20];
  const int* l3 = (const int*)d_in[21];
  const int* m3 = (const int*)d_in[22];
  const int* g3 = (const int*)d_in[23];
  const int* k3 = (const int*)d_in[24];
  const int* q3 = (const int*)d_in[25];

  unsigned* idxs = (unsigned*)d_ws;                    // 416*4 B
  short*    cwb  = (short*)((char*)d_ws + 4096);       // 832 KB

  build_idx_kernel<<<1, 448, 0, stream>>>(i1, l1, i2, j2, l2, m2,
                                          i3, j3, f3, l3, m3, g3, idxs);
  build_cwb_kernel<<<AA * NKS, 64, 0, stream>>>(w1, w2, w3, c1, c2, c3,
                                                k1, q1, k2, q2, k3, q3, cwb);
  contract_kernel<<<(AA / NCH) * (BB / BCH), 256, 0, stream>>>(
      x, y, idxs, (const bf16x8*)cwb, (float*)d_out);
}

// Round 10
// 42.812 us; speedup vs baseline: 3.0142x; 1.1355x over previous
//
#include <hip/hip_runtime.h>
#include <hip/hip_bf16.h>

typedef _Float16 f16x8 __attribute__((ext_vector_type(8)));
typedef _Float16 f16x4 __attribute__((ext_vector_type(4)));
typedef float    f32x4 __attribute__((ext_vector_type(4)));

constexpr int BB  = 4096;
constexpr int AA  = 64;
constexpr int ED  = 10;
constexpr int P1N = 32, P2N = 128, P3N = 256;
constexpr int PT  = 416;          // = 13 * 32
constexpr int NKS = 13;           // K-steps of 32
constexpr int KSPL = 7;           // k-half split: [0,7) / [7,13)
constexpr int BCH = 32;           // b rows per block
constexpr int NCH = 4;            // a-channels per block (fp16x4 per slot)

// ---------------------------------------------------------------------------
// idxs[p] = (sa*8) | (sb*8)<<10 | (sc*8)<<20  -- BYTE offsets into an f16x4
// row (8 B/slot). Unused factors -> slot 64 (constant 1.0): every p is a
// uniform 3-factor product.
// ---------------------------------------------------------------------------
__global__ void build_idx_kernel(
    const int* __restrict__ i1, const int* __restrict__ l1,
    const int* __restrict__ i2, const int* __restrict__ j2,
    const int* __restrict__ l2, const int* __restrict__ m2,
    const int* __restrict__ i3, const int* __restrict__ j3,
    const int* __restrict__ f3, const int* __restrict__ l3,
    const int* __restrict__ m3, const int* __restrict__ g3,
    unsigned* __restrict__ idxs) {
  const int p = threadIdx.x;
  if (p >= PT) return;
  unsigned sa, sb = 64, sc = 64;
  if (p < P1N) {
    sa = i1[p] * 4 + l1[p];
  } else if (p < P1N + P2N) {
    int pp = p - P1N;
    sa = i2[pp] * 4 + l2[pp];
    sb = j2[pp] * 4 + m2[pp];
  } else {
    int pp = p - P1N - P2N;
    sa = i3[pp] * 4 + l3[pp];
    sb = j3[pp] * 4 + m3[pp];
    sc = f3[pp] * 4 + g3[pp];
  }
  idxs[p] = (sa * 8) | ((sb * 8) << 10) | ((sc * 8) << 20);
}

// ---------------------------------------------------------------------------
// B-frag table (fp16): cwb[a][ks][lane][j] = f16( coeff[p] * w[e,k[p],q[p],a] )
// p = ks*32 + (lane>>4)*8 + j, e = lane&15 (0 for e>=10).
// ---------------------------------------------------------------------------
__global__ void build_cwb_kernel(
    const float* __restrict__ w1, const float* __restrict__ w2, const float* __restrict__ w3,
    const float* __restrict__ c1, const float* __restrict__ c2, const float* __restrict__ c3,
    const int* __restrict__ k1, const int* __restrict__ q1,
    const int* __restrict__ k2, const int* __restrict__ q2,
    const int* __restrict__ k3, const int* __restrict__ q3,
    _Float16* __restrict__ cwb) {
  const int a  = blockIdx.x & 63;
  const int ks = blockIdx.x >> 6;   // 0..12
  const int l  = threadIdx.x;       // 0..63
  const int grp = l >> 4, e = l & 15;
  _Float16* dst = cwb + (((size_t)a * NKS + ks) * 64 + l) * 8;
  #pragma unroll
  for (int j = 0; j < 8; ++j) {
    const int p = ks * 32 + grp * 8 + j;
    float v = 0.f;
    if (e < ED) {
      const float* w; float coeff; int k, q, K, Q;
      if (p < P1N)            { w = w1; coeff = c1[p]; k = k1[p]; q = q1[p]; K = 4;  Q = 2; }
      else if (p < P1N + P2N) { int pp = p - P1N;       w = w2; coeff = c2[pp]; k = k2[pp]; q = q2[pp]; K = 16; Q = 4; }
      else                    { int pp = p - P1N - P2N; w = w3; coeff = c3[pp]; k = k3[pp]; q = q3[pp]; K = 32; Q = 6; }
      v = coeff * w[(((size_t)e * K + k) * Q + q) * AA + a];
    }
    dst[j] = (_Float16)v;
  }
}

// ---------------------------------------------------------------------------
// Main: block = a-quad x 32 b's; fp16x4 x-tile. Uniform 3-factor ksteps:
// 24 ds_read_b64 batched -> one wait -> v_pk_mul_f16 products ARE the
// fp16 A-frags -> 4x mfma_f32_16x16x32_f16. No f32 conversion anywhere.
// __launch_bounds__(256,4): 128-VGPR budget, no spill (r8 lesson).
// ---------------------------------------------------------------------------
__global__ __launch_bounds__(256, 4)
void contract_kernel(const float* __restrict__ x, const float* __restrict__ y,
                     const unsigned* __restrict__ idxs,
                     const f16x8* __restrict__ cwb,
                     float* __restrict__ out) {
  __shared__ f16x4 xls[BCH][65];   // slot 64 = {1,1,1,1}; 16.25 KB
  __shared__ float yls[BCH][17];   // e padded to 16 with zeros

  const int t  = threadIdx.x;
  const int a0 = (blockIdx.x & 15) * NCH;
  const int b0 = (blockIdx.x >> 4) * BCH;

  // Stage x: lane = slot; 4 coalesced dword loads -> cvt f16 -> one b64 write.
  for (int u = t; u < BCH * 64; u += 256) {
    const int b = u >> 6, s = u & 63;
    const float* xb = x + (size_t)(b0 + b) * 4096 + a0 * 64 + s;
    f16x4 v;
    v[0] = (_Float16)xb[0];
    v[1] = (_Float16)xb[64];
    v[2] = (_Float16)xb[128];
    v[3] = (_Float16)xb[192];
    xls[b][s] = v;
  }
  if (t < BCH) {
    f16x4 one;
    one[0] = one[1] = one[2] = one[3] = (_Float16)1.0f;
    xls[t][64] = one;
    const float* yb = y + (size_t)(b0 + t) * ED;
    #pragma unroll
    for (int e = 0; e < ED; ++e) yls[t][e] = yb[e];
    #pragma unroll
    for (int e = ED; e < 16; ++e) yls[t][e] = 0.f;
  }
  __syncthreads();

  const int wv = t >> 6, l = t & 63, grp = l >> 4, er = l & 15;
  const int mt = wv & 1;            // M-tile (16 rows)
  const int kh = wv >> 1;           // k-half
  const char* __restrict__ rowb = (const char*)&xls[mt * 16 + er][0];
  const f16x8* __restrict__ cw0 = cwb + ((size_t)(a0 + 0) * NKS) * 64 + l;
  const f16x8* __restrict__ cw1 = cwb + ((size_t)(a0 + 1) * NKS) * 64 + l;
  const f16x8* __restrict__ cw2 = cwb + ((size_t)(a0 + 2) * NKS) * 64 + l;
  const f16x8* __restrict__ cw3 = cwb + ((size_t)(a0 + 3) * NKS) * 64 + l;
  const uint4*  __restrict__ ip  = (const uint4*)idxs + grp * 2;

  f32x4 ac0 = {0.f, 0.f, 0.f, 0.f};
  f32x4 ac1 = {0.f, 0.f, 0.f, 0.f};
  f32x4 ac2 = {0.f, 0.f, 0.f, 0.f};
  f32x4 ac3 = {0.f, 0.f, 0.f, 0.f};

  const int ks_beg = kh ? KSPL : 0;
  const int ks_end = kh ? NKS : KSPL;

  for (int ks = ks_beg; ks < ks_end; ++ks) {
    const uint4 iA = ip[ks * 8 + 0];
    const uint4 iB = ip[ks * 8 + 1];
    const f16x8 b0f = cw0[ks * 64];
    const f16x8 b1f = cw1[ks * 64];
    const f16x8 b2f = cw2[ks * 64];
    const f16x8 b3f = cw3[ks * 64];
    const unsigned pks[8] = {iA.x, iA.y, iA.z, iA.w, iB.x, iB.y, iB.z, iB.w};

    // One big read batch: 24 ds_read_b64, single wait point.
    f16x4 g0[8], g1[8], g2[8];
    #pragma unroll
    for (int j = 0; j < 8; ++j) {
      const unsigned pk = pks[j];
      g0[j] = *(const f16x4*)(rowb + (pk & 1023u));
      g1[j] = *(const f16x4*)(rowb + ((pk >> 10) & 1023u));
      g2[j] = *(const f16x4*)(rowb + (pk >> 20));
    }

    // Products in fp16 (v_pk_mul_f16) -> A-frags directly.
    f16x8 af0, af1, af2, af3;
    #pragma unroll
    for (int j = 0; j < 8; ++j) {
      const f16x4 v = g0[j] * g1[j] * g2[j];
      af0[j] = v[0]; af1[j] = v[1]; af2[j] = v[2]; af3[j] = v[3];
    }

    ac0 = __builtin_amdgcn_mfma_f32_16x16x32_f16(af0, b0f, ac0, 0, 0, 0);
    ac1 = __builtin_amdgcn_mfma_f32_16x16x32_f16(af1, b1f, ac1, 0, 0, 0);
    ac2 = __builtin_amdgcn_mfma_f32_16x16x32_f16(af2, b2f, ac2, 0, 0, 0);
    ac3 = __builtin_amdgcn_mfma_f32_16x16x32_f16(af3, b3f, ac3, 0, 0, 0);
  }

  // Combine k-halves via LDS scratch (stride 17: bijective banks, 8.7 KB).
  __syncthreads();
  float* scr = (float*)&xls[0][0];
  const int sbase = (mt * 64 + l) * 17;
  if (kh == 1) {
    #pragma unroll
    for (int v = 0; v < 4; ++v) {
      scr[sbase + v + 0]  = ac0[v];
      scr[sbase + v + 4]  = ac1[v];
      scr[sbase + v + 8]  = ac2[v];
      scr[sbase + v + 12] = ac3[v];
    }
  }
  __syncthreads();
  if (kh == 0) {
    #pragma unroll
    for (int v = 0; v < 4; ++v) {
      ac0[v] += scr[sbase + v + 0];
      ac1[v] += scr[sbase + v + 4];
      ac2[v] += scr[sbase + v + 8];
      ac3[v] += scr[sbase + v + 12];
    }
    // Epilogue: D[row = mt*16+grp*4+v][col = er], y-weight, reduce over e.
    #pragma unroll
    for (int c = 0; c < NCH; ++c) {
      const f32x4 acc = c == 0 ? ac0 : c == 1 ? ac1 : c == 2 ? ac2 : ac3;
      float s0 = acc[0] * yls[mt * 16 + grp * 4 + 0][er];
      float s1 = acc[1] * yls[mt * 16 + grp * 4 + 1][er];
      float s2 = acc[2] * yls[mt * 16 + grp * 4 + 2][er];
      float s3 = acc[3] * yls[mt * 16 + grp * 4 + 3][er];
      #pragma unroll
      for (int m = 1; m < 16; m <<= 1) {
        s0 += __shfl_xor(s0, m);
        s1 += __shfl_xor(s1, m);
        s2 += __shfl_xor(s2, m);
        s3 += __shfl_xor(s3, m);
      }
      if (er < 4) {
        const float sv = er == 0 ? s0 : er == 1 ? s1 : er == 2 ? s2 : s3;
        out[(size_t)(b0 + mt * 16 + grp * 4 + er) * AA + (a0 + c)] = sv;
      }
    }
  }
}

// ---------------------------------------------------------------------------
extern "C" void kernel_launch(void* const* d_in, const int* in_sizes, int n_in,
                              void* d_out, int out_size, void* d_ws, size_t ws_size,
                              hipStream_t stream) {
  const float* x  = (const float*)d_in[0];
  const float* y  = (const float*)d_in[1];
  const float* w1 = (const float*)d_in[2];
  const float* w2 = (const float*)d_in[3];
  const float* w3 = (const float*)d_in[4];
  const float* c1 = (const float*)d_in[5];
  const float* c2 = (const float*)d_in[6];
  const float* c3 = (const float*)d_in[7];
  const int* i1 = (const int*)d_in[8];
  const int* l1 = (const int*)d_in[9];
  const int* k1 = (const int*)d_in[10];
  const int* q1 = (const int*)d_in[11];
  const int* i2 = (const int*)d_in[12];
  const int* j2 = (const int*)d_in[13];
  const int* l2 = (const int*)d_in[14];
  const int* m2 = (const int*)d_in[15];
  const int* k2 = (const int*)d_in[16];
  const int* q2 = (const int*)d_in[17];
  const int* i3 = (const int*)d_in[18];
  const int* j3 = (const int*)d_in[19];
  const int* f3 = (const int*)d_in[20];
  const int* l3 = (const int*)d_in[21];
  const int* m3 = (const int*)d_in[22];
  const int* g3 = (const int*)d_in[23];
  const int* k3 = (const int*)d_in[24];
  const int* q3 = (const int*)d_in[25];

  unsigned*  idxs = (unsigned*)d_ws;                    // 416*4 B
  _Float16*  cwb  = (_Float16*)((char*)d_ws + 4096);    // 832 KB

  build_idx_kernel<<<1, 448, 0, stream>>>(i1, l1, i2, j2, l2, m2,
                                          i3, j3, f3, l3, m3, g3, idxs);
  build_cwb_kernel<<<AA * NKS, 64, 0, stream>>>(w1, w2, w3, c1, c2, c3,
                                                k1, q1, k2, q2, k3, q3, cwb);
  contract_kernel<<<(AA / NCH) * (BB / BCH), 256, 0, stream>>>(
      x, y, idxs, (const f16x8*)cwb, (float*)d_out);
}

// Round 11
// 40.225 us; speedup vs baseline: 3.2080x; 1.0643x over previous
//
#include <hip/hip_runtime.h>
#include <hip/hip_bf16.h>

typedef _Float16 f16x8 __attribute__((ext_vector_type(8)));
typedef _Float16 f16x4 __attribute__((ext_vector_type(4)));
typedef float    f32x4 __attribute__((ext_vector_type(4)));

constexpr int BB  = 4096;
constexpr int AA  = 64;
constexpr int ED  = 10;
constexpr int P1N = 32, P2N = 128, P3N = 256;
constexpr int PT  = 416;          // = 13 * 32
constexpr int NKS = 13;           // K-steps of 32
constexpr int BCH = 64;           // b rows per block
constexpr int NCH = 4;            // a-channels per block (fp16x4 per slot)

// ---------------------------------------------------------------------------
// idxs[p] = (sa*8) | (sb*8)<<10 | (sc*8)<<20  -- BYTE offsets into an f16x4
// row (8 B/slot). Unused factors -> slot 64 (constant 1.0).
// ---------------------------------------------------------------------------
__global__ void build_idx_kernel(
    const int* __restrict__ i1, const int* __restrict__ l1,
    const int* __restrict__ i2, const int* __restrict__ j2,
    const int* __restrict__ l2, const int* __restrict__ m2,
    const int* __restrict__ i3, const int* __restrict__ j3,
    const int* __restrict__ f3, const int* __restrict__ l3,
    const int* __restrict__ m3, const int* __restrict__ g3,
    unsigned* __restrict__ idxs) {
  const int p = threadIdx.x;
  if (p >= PT) return;
  unsigned sa, sb = 64, sc = 64;
  if (p < P1N) {
    sa = i1[p] * 4 + l1[p];
  } else if (p < P1N + P2N) {
    int pp = p - P1N;
    sa = i2[pp] * 4 + l2[pp];
    sb = j2[pp] * 4 + m2[pp];
  } else {
    int pp = p - P1N - P2N;
    sa = i3[pp] * 4 + l3[pp];
    sb = j3[pp] * 4 + m3[pp];
    sc = f3[pp] * 4 + g3[pp];
  }
  idxs[p] = (sa * 8) | ((sb * 8) << 10) | ((sc * 8) << 20);
}

// ---------------------------------------------------------------------------
// B-frag table (fp16): cwb[a][ks][lane][j] = f16( coeff[p] * w[e,k[p],q[p],a] )
// p = ks*32 + (lane>>4)*8 + j, e = lane&15 (0 for e>=10).
// ---------------------------------------------------------------------------
__global__ void build_cwb_kernel(
    const float* __restrict__ w1, const float* __restrict__ w2, const float* __restrict__ w3,
    const float* __restrict__ c1, const float* __restrict__ c2, const float* __restrict__ c3,
    const int* __restrict__ k1, const int* __restrict__ q1,
    const int* __restrict__ k2, const int* __restrict__ q2,
    const int* __restrict__ k3, const int* __restrict__ q3,
    _Float16* __restrict__ cwb) {
  const int a  = blockIdx.x & 63;
  const int ks = blockIdx.x >> 6;   // 0..12
  const int l  = threadIdx.x;       // 0..63
  const int grp = l >> 4, e = l & 15;
  _Float16* dst = cwb + (((size_t)a * NKS + ks) * 64 + l) * 8;
  #pragma unroll
  for (int j = 0; j < 8; ++j) {
    const int p = ks * 32 + grp * 8 + j;
    float v = 0.f;
    if (e < ED) {
      const float* w; float coeff; int k, q, K, Q;
      if (p < P1N)            { w = w1; coeff = c1[p]; k = k1[p]; q = q1[p]; K = 4;  Q = 2; }
      else if (p < P1N + P2N) { int pp = p - P1N;       w = w2; coeff = c2[pp]; k = k2[pp]; q = q2[pp]; K = 16; Q = 4; }
      else                    { int pp = p - P1N - P2N; w = w3; coeff = c3[pp]; k = k3[pp]; q = q3[pp]; K = 32; Q = 6; }
      v = coeff * w[(((size_t)e * K + k) * Q + q) * AA + a];
    }
    dst[j] = (_Float16)v;
  }
}

// ---------------------------------------------------------------------------
// One K-step, software-pipelined: FIRST issue next kstep's idx + B-frag
// global loads (L2-latency hidden under this step's work), THEN gather
// (NF-specialized, two 12-read sub-batches), multiply in fp16, 4x MFMA.
// Current state passed by value; next state written to out-refs (caller
// aliases them to the same variables -- copies made at call entry).
// ---------------------------------------------------------------------------
template <int NF, int KS, bool LAST>
__device__ __forceinline__ void kstep(
    const char* __restrict__ rowb, const uint4* __restrict__ ip,
    const f16x8* __restrict__ cw0, const f16x8* __restrict__ cw1,
    const f16x8* __restrict__ cw2, const f16x8* __restrict__ cw3,
    uint4 iA, uint4 iB,
    f16x8 b0, f16x8 b1, f16x8 b2, f16x8 b3,
    uint4& nA, uint4& nB,
    f16x8& n0, f16x8& n1, f16x8& n2, f16x8& n3,
    f32x4& ac0, f32x4& ac1, f32x4& ac2, f32x4& ac3) {
  if constexpr (!LAST) {
    nA = ip[(KS + 1) * 8];
    nB = ip[(KS + 1) * 8 + 1];
    n0 = cw0[(KS + 1) * 64];
    n1 = cw1[(KS + 1) * 64];
    n2 = cw2[(KS + 1) * 64];
    n3 = cw3[(KS + 1) * 64];
  }
  const unsigned pks[8] = {iA.x, iA.y, iA.z, iA.w, iB.x, iB.y, iB.z, iB.w};
  f16x8 af0, af1, af2, af3;
  #pragma unroll
  for (int jh = 0; jh < 2; ++jh) {
    f16x4 g0[4], g1[4], g2[4];
    #pragma unroll
    for (int j = 0; j < 4; ++j) {
      const unsigned pk = pks[jh * 4 + j];
      g0[j] = *(const f16x4*)(rowb + (pk & 1023u));
      if (NF >= 2) g1[j] = *(const f16x4*)(rowb + ((pk >> 10) & 1023u));
      if (NF >= 3) g2[j] = *(const f16x4*)(rowb + (pk >> 20));
    }
    #pragma unroll
    for (int j = 0; j < 4; ++j) {
      f16x4 v = g0[j];
      if (NF >= 2) v = v * g1[j];
      if (NF >= 3) v = v * g2[j];
      const int jj = jh * 4 + j;
      af0[jj] = v[0]; af1[jj] = v[1]; af2[jj] = v[2]; af3[jj] = v[3];
    }
  }
  ac0 = __builtin_amdgcn_mfma_f32_16x16x32_f16(af0, b0, ac0, 0, 0, 0);
  ac1 = __builtin_amdgcn_mfma_f32_16x16x32_f16(af1, b1, ac1, 0, 0, 0);
  ac2 = __builtin_amdgcn_mfma_f32_16x16x32_f16(af2, b2, ac2, 0, 0, 0);
  ac3 = __builtin_amdgcn_mfma_f32_16x16x32_f16(af3, b3, ac3, 0, 0, 0);
}

// ---------------------------------------------------------------------------
// Main: block = a-quad x 64 b's; 4 waves = 4 M-tiles (no k-split).
// Straight-line 13 ksteps, 1-ahead prefetch. 37.6 KB LDS -> 4 blocks/CU;
// grid 1024 = exactly 4/CU, one round. (256,4): 128-VGPR budget, no spill.
// ---------------------------------------------------------------------------
__global__ __launch_bounds__(256, 4)
void contract_kernel(const float* __restrict__ x, const float* __restrict__ y,
                     const unsigned* __restrict__ idxs,
                     const f16x8* __restrict__ cwb,
                     float* __restrict__ out) {
  __shared__ f16x4 xls[BCH][65];   // slot 64 = {1,1,1,1}; 33.3 KB
  __shared__ float yls[BCH][17];   // e padded to 16 with zeros

  const int t  = threadIdx.x;
  const int a0 = (blockIdx.x & 15) * NCH;
  const int b0 = (blockIdx.x >> 4) * BCH;

  // Stage x: lane = slot; 4 coalesced dword loads -> cvt f16 -> one b64 write.
  for (int u = t; u < BCH * 64; u += 256) {
    const int b = u >> 6, s = u & 63;
    const float* xb = x + (size_t)(b0 + b) * 4096 + a0 * 64 + s;
    f16x4 v;
    v[0] = (_Float16)xb[0];
    v[1] = (_Float16)xb[64];
    v[2] = (_Float16)xb[128];
    v[3] = (_Float16)xb[192];
    xls[b][s] = v;
  }
  if (t < BCH) {
    f16x4 one;
    one[0] = one[1] = one[2] = one[3] = (_Float16)1.0f;
    xls[t][64] = one;
    const float* yb = y + (size_t)(b0 + t) * ED;
    #pragma unroll
    for (int e = 0; e < ED; ++e) yls[t][e] = yb[e];
    #pragma unroll
    for (int e = ED; e < 16; ++e) yls[t][e] = 0.f;
  }
  __syncthreads();

  const int wv = t >> 6, l = t & 63, grp = l >> 4, er = l & 15;
  const char* __restrict__ rowb = (const char*)&xls[wv * 16 + er][0];
  const f16x8* __restrict__ cw0 = cwb + ((size_t)(a0 + 0) * NKS) * 64 + l;
  const f16x8* __restrict__ cw1 = cwb + ((size_t)(a0 + 1) * NKS) * 64 + l;
  const f16x8* __restrict__ cw2 = cwb + ((size_t)(a0 + 2) * NKS) * 64 + l;
  const f16x8* __restrict__ cw3 = cwb + ((size_t)(a0 + 3) * NKS) * 64 + l;
  const uint4*  __restrict__ ip  = (const uint4*)idxs + grp * 2;

  f32x4 ac0 = {0.f, 0.f, 0.f, 0.f};
  f32x4 ac1 = {0.f, 0.f, 0.f, 0.f};
  f32x4 ac2 = {0.f, 0.f, 0.f, 0.f};
  f32x4 ac3 = {0.f, 0.f, 0.f, 0.f};

  // Prologue: load kstep 0's idx + B-frags.
  uint4 cA = ip[0], cB = ip[1];
  f16x8 cb0 = cw0[0], cb1 = cw1[0], cb2 = cw2[0], cb3 = cw3[0];

  #define STEP(NF, KS, LAST)                                                  \
    kstep<NF, KS, LAST>(rowb, ip, cw0, cw1, cw2, cw3, cA, cB,                 \
                        cb0, cb1, cb2, cb3, cA, cB, cb0, cb1, cb2, cb3,       \
                        ac0, ac1, ac2, ac3)
  STEP(1, 0, false);                                      // path 1
  STEP(2, 1, false); STEP(2, 2, false);                   // path 2
  STEP(2, 3, false); STEP(2, 4, false);
  STEP(3, 5, false); STEP(3, 6, false); STEP(3, 7, false);  // path 3
  STEP(3, 8, false); STEP(3, 9, false); STEP(3, 10, false);
  STEP(3, 11, false); STEP(3, 12, true);
  #undef STEP

  // Epilogue: D[row = grp*4+v][col = er], y-weight, 16-lane reduce over e.
  #pragma unroll
  for (int c = 0; c < NCH; ++c) {
    const f32x4 acc = c == 0 ? ac0 : c == 1 ? ac1 : c == 2 ? ac2 : ac3;
    float s0 = acc[0] * yls[wv * 16 + grp * 4 + 0][er];
    float s1 = acc[1] * yls[wv * 16 + grp * 4 + 1][er];
    float s2 = acc[2] * yls[wv * 16 + grp * 4 + 2][er];
    float s3 = acc[3] * yls[wv * 16 + grp * 4 + 3][er];
    #pragma unroll
    for (int m = 1; m < 16; m <<= 1) {
      s0 += __shfl_xor(s0, m);
      s1 += __shfl_xor(s1, m);
      s2 += __shfl_xor(s2, m);
      s3 += __shfl_xor(s3, m);
    }
    if (er < 4) {
      const float sv = er == 0 ? s0 : er == 1 ? s1 : er == 2 ? s2 : s3;
      out[(size_t)(b0 + wv * 16 + grp * 4 + er) * AA + (a0 + c)] = sv;
    }
  }
}

// ---------------------------------------------------------------------------
extern "C" void kernel_launch(void* const* d_in, const int* in_sizes, int n_in,
                              void* d_out, int out_size, void* d_ws, size_t ws_size,
                              hipStream_t stream) {
  const float* x  = (const float*)d_in[0];
  const float* y  = (const float*)d_in[1];
  const float* w1 = (const float*)d_in[2];
  const float* w2 = (const float*)d_in[3];
  const float* w3 = (const float*)d_in[4];
  const float* c1 = (const float*)d_in[5];
  const float* c2 = (const float*)d_in[6];
  const float* c3 = (const float*)d_in[7];
  const int* i1 = (const int*)d_in[8];
  const int* l1 = (const int*)d_in[9];
  const int* k1 = (const int*)d_in[10];
  const int* q1 = (const int*)d_in[11];
  const int* i2 = (const int*)d_in[12];
  const int* j2 = (const int*)d_in[13];
  const int* l2 = (const int*)d_in[14];
  const int* m2 = (const int*)d_in[15];
  const int* k2 = (const int*)d_in[16];
  const int* q2 = (const int*)d_in[17];
  const int* i3 = (const int*)d_in[18];
  const int* j3 = (const int*)d_in[19];
  const int* f3 = (const int*)d_in[20];
  const int* l3 = (const int*)d_in[21];
  const int* m3 = (const int*)d_in[22];
  const int* g3 = (const int*)d_in[23];
  const int* k3 = (const int*)d_in[24];
  const int* q3 = (const int*)d_in[25];

  unsigned*  idxs = (unsigned*)d_ws;                    // 416*4 B
  _Float16*  cwb  = (_Float16*)((char*)d_ws + 4096);    // 832 KB

  build_idx_kernel<<<1, 448, 0, stream>>>(i1, l1, i2, j2, l2, m2,
                                          i3, j3, f3, l3, m3, g3, idxs);
  build_cwb_kernel<<<AA * NKS, 64, 0, stream>>>(w1, w2, w3, c1, c2, c3,
                                                k1, q1, k2, q2, k3, q3, cwb);
  contract_kernel<<<(AA / NCH) * (BB / BCH), 256, 0, stream>>>(
      x, y, idxs, (const f16x8*)cwb, (float*)d_out);
}